// Round 12
// baseline (212.681 us; speedup 1.0000x reference)
//
#include <hip/hip_runtime.h>

// B=2,S=2048,H=1024,NH=16,HD=64 fused attention block.
// Round 12: attn un-paired to 1024 wgs x 256 thr (one 64-q tile each) with a
//           stride-32-balanced per-XCD order (rounds Desc/Asc/Asc/Desc: CU i
//           always sums to 66 steps). 3 blocks/CU by LDS -> 12 waves/CU.
//           Body = R9 validated loop. GEMMs (512-thr reg-prefetch)/cast/LN = R11.
#define B_  2
#define S_  2048
#define H_  1024
#define NH_ 16
#define HD_ 64
#define M_  (B_*S_)   // 4096 rows

typedef __attribute__((ext_vector_type(8))) __bf16 bf16x8;
typedef __attribute__((ext_vector_type(4))) float  f32x4;
typedef __attribute__((ext_vector_type(8))) unsigned short us8;
typedef __attribute__((ext_vector_type(4))) float  fl4;

__device__ __forceinline__ unsigned short f2bf(float f) {
    unsigned int u = __float_as_uint(f);
    u += 0x7fffu + ((u >> 16) & 1u);          // round-to-nearest-even
    return (unsigned short)(u >> 16);
}

// ---------------- cast fp32 -> bf16 (x and the 4 weights) ----------------
__global__ __launch_bounds__(256) void cast_kernel(
    const float* __restrict__ x,
    const float* __restrict__ wq, const float* __restrict__ wk,
    const float* __restrict__ wv, const float* __restrict__ wo,
    unsigned short* __restrict__ xb, unsigned short* __restrict__ wb) {
    size_t t  = (size_t)blockIdx.x * 256 + threadIdx.x;
    size_t e0 = t * 4;
    const size_t XN = (size_t)M_ * H_;        // 4M
    const float* src;
    unsigned short* dst;
    if (e0 < XN) { src = x + e0; dst = xb + e0; }
    else {
        size_t j = e0 - XN;                    // 0..4M over 4 weights of 1M
        int w = (int)(j >> 20);
        size_t off = j & ((1u << 20) - 1);
        const float* wp = (w == 0) ? wq : (w == 1) ? wk : (w == 2) ? wv : wo;
        src = wp + off; dst = wb + j;
    }
    fl4 v = *(const fl4*)src;
    ushort4 o;
    o.x = f2bf(v.x); o.y = f2bf(v.y); o.z = f2bf(v.z); o.w = f2bf(v.w);
    *(ushort4*)dst = o;
}

// ---------------- QKV GEMM (128x128, 512 thr, reg-prefetch) — R11 ----------
// z==0 -> Q (pre-scaled by 1/8*log2e) ; z==1 -> K ; z==2 -> V transposed.
__global__ __launch_bounds__(512) void gemm_qkv(
    const unsigned short* __restrict__ xb, const unsigned short* __restrict__ wb,
    const float* __restrict__ bq, const float* __restrict__ bk,
    const float* __restrict__ bv,
    unsigned short* __restrict__ qb, unsigned short* __restrict__ kbuf,
    unsigned short* __restrict__ vT) {
    __shared__ __align__(16) unsigned short As[128 * 72];
    __shared__ __align__(16) unsigned short Bs[128 * 72];
    const int z = blockIdx.z;
    const unsigned short* W = wb + ((size_t)z << 20);
    const int m0 = blockIdx.x * 128, n0 = blockIdx.y * 128;
    const int t = threadIdx.x, lane = t & 63, w = t >> 6;   // w 0..7
    const int wm = w >> 2, wn = w & 3;                      // 2m x 4n
    const int quad = lane >> 4, l16 = lane & 15;
    const int sr = t >> 2, sc = (t & 3) * 16;               // staging row/col
    const unsigned short* ga = xb + (size_t)(m0 + sr) * H_ + sc;
    const unsigned short* gb = W  + (size_t)(n0 + sr) * H_ + sc;

    us8 a0 = *(const us8*)(ga),     a1 = *(const us8*)(ga + 8);
    us8 b0 = *(const us8*)(gb),     b1 = *(const us8*)(gb + 8);

    f32x4 acc[4][2] = {};
    for (int k0 = 0; k0 < H_; k0 += 64) {
        if (k0) __syncthreads();        // LDS readers of previous kstep done
        *(us8*)&As[sr * 72 + sc]     = a0;  *(us8*)&As[sr * 72 + sc + 8] = a1;
        *(us8*)&Bs[sr * 72 + sc]     = b0;  *(us8*)&Bs[sr * 72 + sc + 8] = b1;
        __syncthreads();                 // tile published
        if (k0 + 64 < H_) {              // prefetch next tile (flies under MFMA)
            ga += 64; gb += 64;
            a0 = *(const us8*)(ga);  a1 = *(const us8*)(ga + 8);
            b0 = *(const us8*)(gb);  b1 = *(const us8*)(gb + 8);
        }
#pragma unroll
        for (int kk = 0; kk < 64; kk += 32) {
            bf16x8 af[4], bfr[2];
#pragma unroll
            for (int i = 0; i < 4; i++)
                af[i]  = *(const bf16x8*)&As[(wm * 64 + i * 16 + l16) * 72 + kk + quad * 8];
#pragma unroll
            for (int jn = 0; jn < 2; jn++)
                bfr[jn] = *(const bf16x8*)&Bs[(wn * 32 + jn * 16 + l16) * 72 + kk + quad * 8];
#pragma unroll
            for (int mi = 0; mi < 4; mi++)
#pragma unroll
                for (int ni = 0; ni < 2; ni++)
                    acc[mi][ni] = __builtin_amdgcn_mfma_f32_16x16x32_bf16(
                        af[mi], bfr[ni], acc[mi][ni], 0, 0, 0);
        }
    }
    const float* bias = (z == 0) ? bq : (z == 1) ? bk : bv;
    if (z == 2) {
#pragma unroll
        for (int mi = 0; mi < 4; mi++) {
#pragma unroll
            for (int ni = 0; ni < 2; ni++) {
                int col  = n0 + wn * 32 + ni * 16 + l16;   // h*64+d
                float bval = bias[col];
                int row0 = m0 + wm * 64 + mi * 16 + quad * 4;  // b*2048+s
                int bb = row0 >> 11, s0 = row0 & 2047;
                ushort4 pk;
                pk.x = f2bf(acc[mi][ni][0] + bval);
                pk.y = f2bf(acc[mi][ni][1] + bval);
                pk.z = f2bf(acc[mi][ni][2] + bval);
                pk.w = f2bf(acc[mi][ni][3] + bval);
                *(ushort4*)&vT[((size_t)bb * NH_ * HD_ + col) * S_ + s0] = pk;
            }
        }
    } else {
        unsigned short* out = (z == 0) ? qb : kbuf;
        const float qs = (z == 0) ? 0.18033688f : 1.0f;   // (1/8)*log2(e) folded into Q
#pragma unroll
        for (int mi = 0; mi < 4; mi++) {
#pragma unroll
            for (int ni = 0; ni < 2; ni++) {
                int col = n0 + wn * 32 + ni * 16 + l16;
                float bval = bias[col];
#pragma unroll
                for (int r = 0; r < 4; r++) {
                    int row = m0 + wm * 64 + mi * 16 + quad * 4 + r;
                    out[(size_t)row * H_ + col] = f2bf((acc[mi][ni][r] + bval) * qs);
                }
            }
        }
    }
}

// ---------------- Wo GEMM + bias + residual (128x128, 512 thr) — R11 -------
__global__ __launch_bounds__(512) void gemm_out(
    const unsigned short* __restrict__ ctxb, const unsigned short* __restrict__ wob,
    const float* __restrict__ bo, const float* __restrict__ x,
    float* __restrict__ y) {
    __shared__ __align__(16) unsigned short As[128 * 72];
    __shared__ __align__(16) unsigned short Bs[128 * 72];
    const int m0 = blockIdx.x * 128, n0 = blockIdx.y * 128;
    const int t = threadIdx.x, lane = t & 63, w = t >> 6;
    const int wm = w >> 2, wn = w & 3;
    const int quad = lane >> 4, l16 = lane & 15;
    const int sr = t >> 2, sc = (t & 3) * 16;
    const unsigned short* ga = ctxb + (size_t)(m0 + sr) * H_ + sc;
    const unsigned short* gb = wob  + (size_t)(n0 + sr) * H_ + sc;

    us8 a0 = *(const us8*)(ga),     a1 = *(const us8*)(ga + 8);
    us8 b0 = *(const us8*)(gb),     b1 = *(const us8*)(gb + 8);

    f32x4 acc[4][2] = {};
    for (int k0 = 0; k0 < H_; k0 += 64) {
        if (k0) __syncthreads();
        *(us8*)&As[sr * 72 + sc]     = a0;  *(us8*)&As[sr * 72 + sc + 8] = a1;
        *(us8*)&Bs[sr * 72 + sc]     = b0;  *(us8*)&Bs[sr * 72 + sc + 8] = b1;
        __syncthreads();
        if (k0 + 64 < H_) {
            ga += 64; gb += 64;
            a0 = *(const us8*)(ga);  a1 = *(const us8*)(ga + 8);
            b0 = *(const us8*)(gb);  b1 = *(const us8*)(gb + 8);
        }
#pragma unroll
        for (int kk = 0; kk < 64; kk += 32) {
            bf16x8 af[4], bfr[2];
#pragma unroll
            for (int i = 0; i < 4; i++)
                af[i]  = *(const bf16x8*)&As[(wm * 64 + i * 16 + l16) * 72 + kk + quad * 8];
#pragma unroll
            for (int jn = 0; jn < 2; jn++)
                bfr[jn] = *(const bf16x8*)&Bs[(wn * 32 + jn * 16 + l16) * 72 + kk + quad * 8];
#pragma unroll
            for (int mi = 0; mi < 4; mi++)
#pragma unroll
                for (int ni = 0; ni < 2; ni++)
                    acc[mi][ni] = __builtin_amdgcn_mfma_f32_16x16x32_bf16(
                        af[mi], bfr[ni], acc[mi][ni], 0, 0, 0);
        }
    }
#pragma unroll
    for (int mi = 0; mi < 4; mi++) {
#pragma unroll
        for (int ni = 0; ni < 2; ni++) {
            int col = n0 + wn * 32 + ni * 16 + l16;
            float bval = bo[col];
#pragma unroll
            for (int r = 0; r < 4; r++) {
                size_t idx = (size_t)(m0 + wm * 64 + mi * 16 + quad * 4 + r) * H_ + col;
                y[idx] = acc[mi][ni][r] + bval + x[idx];
            }
        }
    }
}

// ---------------- Flash attention (causal), balanced 1024 wgs --------------
// One 64-q tile per 256-thr wg. Per XCD: 4 rounds (bh) x 32 tiles, ordered
// Desc/Asc/Asc/Desc so a stride-32 static CU assignment sums to 66 steps
// for every CU. Body = R9: transposed-S softmax (lane owns one q), dbuf LDS
// + register prefetch, 1 barrier/step.
__global__ __launch_bounds__(256) void attn_kernel(
    const unsigned short* __restrict__ qb, const unsigned short* __restrict__ kb,
    const unsigned short* __restrict__ vT, unsigned short* __restrict__ ctxb) {
    __shared__ __align__(16) unsigned short Ks[2][64 * 72];   // [key][d]
    __shared__ __align__(16) unsigned short Vt[2][64 * 72];   // [d][key]
    __shared__ __align__(16) unsigned short Ps[64 * 76];      // [q][key] per wave
    const int flat = blockIdx.x;                  // 0..1023
    const int xcd = flat & 7, slot = flat >> 3;   // slot 0..127
    const int round = slot >> 5, i = slot & 31;
    const int qt = (round == 0 || round == 3) ? (31 - i) : i;
    const int bh = xcd * 4 + round;
    const int b = bh >> 4, h = bh & 15;
    const int t = threadIdx.x, lane = t & 63, wid = t >> 6;
    const int quad = lane >> 4, l16 = lane & 15;
    const int sr = t >> 2, sc = (t & 3) * 16;
    const size_t headoff = (size_t)h * HD_;
    const unsigned short* vtb = vT + ((size_t)(b * NH_ + h) * HD_) * S_;  // [d][s]
    const int q0 = qt * 64;

    // Q fragment: lane l16 holds query q0+wid*16+l16, d = quad*8+j (B-operand)
    const size_t qrow = (size_t)(b * S_ + q0 + wid * 16 + l16);
    bf16x8 qf0 = *(const bf16x8*)(qb + qrow * H_ + headoff + quad * 8);   // pre-scaled
    bf16x8 qf1 = *(const bf16x8*)(qb + qrow * H_ + headoff + 32 + quad * 8);

    float m_r = -1e30f, l_r = 0.f;    // per-lane (one query)
    f32x4 o_acc[4] = {};              // O^T: d = dt*16+quad*4+r, q = l16

    // preload tile 0 into registers
    const unsigned short* kptr = kb  + (size_t)(b * S_ + sr) * H_ + headoff + sc;
    const unsigned short* vptr = vtb + (size_t)sr * S_ + sc;
    us8 nk0 = *(const us8*)(kptr);
    us8 nk1 = *(const us8*)(kptr + 8);
    us8 nv0 = *(const us8*)(vptr);
    us8 nv1 = *(const us8*)(vptr + 8);
    *(us8*)&Ks[0][sr * 72 + sc]     = nk0;  *(us8*)&Ks[0][sr * 72 + sc + 8] = nk1;
    *(us8*)&Vt[0][sr * 72 + sc]     = nv0;  *(us8*)&Vt[0][sr * 72 + sc + 8] = nv1;
    __syncthreads();

    for (int s = 0; s <= qt; s++) {
        const int buf = s & 1;
        const bool pf = (s < qt);
        if (pf) {   // prefetch next tile into registers (hidden under compute)
            kptr += (size_t)64 * H_;
            vptr += 64;
            nk0 = *(const us8*)(kptr);
            nk1 = *(const us8*)(kptr + 8);
            nv0 = *(const us8*)(vptr);
            nv1 = *(const us8*)(vptr + 8);
        }
        // S^T = K Q^T: A = K (m=key), B = Q (n=q) -> C[key][q]
        f32x4 sacc[4] = {};
#pragma unroll
        for (int kk = 0; kk < 64; kk += 32) {
            bf16x8 bq_ = (kk == 0) ? qf0 : qf1;
#pragma unroll
            for (int nt = 0; nt < 4; nt++) {
                bf16x8 ak = *(const bf16x8*)&Ks[buf][(nt * 16 + l16) * 72 + kk + quad * 8];
                sacc[nt] = __builtin_amdgcn_mfma_f32_16x16x32_bf16(ak, bq_, sacc[nt], 0, 0, 0);
            }
        }
        if (s == qt) {   // causal mask, diagonal tile only (wave-uniform branch)
#pragma unroll
            for (int nt = 0; nt < 4; nt++) {
#pragma unroll
                for (int r = 0; r < 4; r++) {
                    int key = nt * 16 + quad * 4 + r;
                    if (key > wid * 16 + l16) sacc[nt][r] = -1e30f;
                }
            }
        }
        // online softmax (base-2): in-lane over 16 keys + 2 cross-quad shuffles
        float mx = sacc[0][0];
#pragma unroll
        for (int nt = 0; nt < 4; nt++)
#pragma unroll
            for (int r = 0; r < 4; r++) mx = fmaxf(mx, sacc[nt][r]);
        mx = fmaxf(mx, __shfl_xor(mx, 16));
        mx = fmaxf(mx, __shfl_xor(mx, 32));
        float m_new = fmaxf(m_r, mx);
        float alpha = exp2f(m_r - m_new);
        float ss = 0.f;
#pragma unroll
        for (int nt = 0; nt < 4; nt++) {
            ushort4 pk;
            float p0 = exp2f(sacc[nt][0] - m_new);
            float p1 = exp2f(sacc[nt][1] - m_new);
            float p2 = exp2f(sacc[nt][2] - m_new);
            float p3 = exp2f(sacc[nt][3] - m_new);
            ss += (p0 + p1) + (p2 + p3);
            pk.x = (unsigned short)(__float_as_uint(p0) >> 16);
            pk.y = (unsigned short)(__float_as_uint(p1) >> 16);
            pk.z = (unsigned short)(__float_as_uint(p2) >> 16);
            pk.w = (unsigned short)(__float_as_uint(p3) >> 16);
            // Ps[q][key]: q = wid*16+l16, keys nt*16+quad*4..+3 (8B write)
            *(ushort4*)&Ps[(wid * 16 + l16) * 76 + nt * 16 + quad * 4] = pk;
        }
        ss += __shfl_xor(ss, 16);
        ss += __shfl_xor(ss, 32);
        l_r = l_r * alpha + ss;
        m_r = m_new;
#pragma unroll
        for (int dt = 0; dt < 4; dt++)
#pragma unroll
            for (int r = 0; r < 4; r++) o_acc[dt][r] *= alpha;
        __threadfence_block();   // order same-wave LDS write->read
        // O^T += V^T P: A = V^T (m=d), B = P (n=q)
#pragma unroll
        for (int kk = 0; kk < 64; kk += 32) {
            bf16x8 pfr = *(const bf16x8*)&Ps[(wid * 16 + l16) * 76 + kk + quad * 8];
#pragma unroll
            for (int dt = 0; dt < 4; dt++) {
                bf16x8 vf = *(const bf16x8*)&Vt[buf][(dt * 16 + l16) * 72 + kk + quad * 8];
                o_acc[dt] = __builtin_amdgcn_mfma_f32_16x16x32_bf16(vf, pfr, o_acc[dt], 0, 0, 0);
            }
        }
        if (pf) {   // publish prefetched tile; single barrier per step
            *(us8*)&Ks[buf ^ 1][sr * 72 + sc]     = nk0;
            *(us8*)&Ks[buf ^ 1][sr * 72 + sc + 8] = nk1;
            *(us8*)&Vt[buf ^ 1][sr * 72 + sc]     = nv0;
            *(us8*)&Vt[buf ^ 1][sr * 72 + sc + 8] = nv1;
            __syncthreads();
        }
    }
    // normalize + store ctx: lane q = l16, d = dt*16+quad*4+r (8B packs)
    {
        float inv = 1.0f / l_r;
        size_t row = (size_t)(b * S_ + q0 + wid * 16 + l16);
#pragma unroll
        for (int dt = 0; dt < 4; dt++) {
            ushort4 pk;
            pk.x = f2bf(o_acc[dt][0] * inv);
            pk.y = f2bf(o_acc[dt][1] * inv);
            pk.z = f2bf(o_acc[dt][2] * inv);
            pk.w = f2bf(o_acc[dt][3] * inv);
            *(ushort4*)&ctxb[row * H_ + headoff + dt * 16 + quad * 4] = pk;
        }
    }
}

// ---------------- LayerNorm (1 block per row) ----------------
__global__ __launch_bounds__(256) void ln_kernel(
    const float* __restrict__ y, const float* __restrict__ g,
    const float* __restrict__ bta, float* __restrict__ out) {
    __shared__ float red[8];
    const int row = blockIdx.x, t = threadIdx.x;
    fl4 v = *(const fl4*)(y + (size_t)row * H_ + t * 4);
    float s  = v.x + v.y + v.z + v.w;
    float sq = v.x * v.x + v.y * v.y + v.z * v.z + v.w * v.w;
    for (int m = 1; m < 64; m <<= 1) { s += __shfl_xor(s, m); sq += __shfl_xor(sq, m); }
    const int wid = t >> 6, lane = t & 63;
    if (lane == 0) { red[wid * 2] = s; red[wid * 2 + 1] = sq; }
    __syncthreads();
    s  = red[0] + red[2] + red[4] + red[6];
    sq = red[1] + red[3] + red[5] + red[7];
    float mu   = s * (1.0f / H_);
    float var  = sq * (1.0f / H_) - mu * mu;
    float rstd = rsqrtf(fmaxf(var, 0.f) + 1e-12f);
    fl4 gg = *(const fl4*)(g + t * 4);
    fl4 bb = *(const fl4*)(bta + t * 4);
    fl4 o;
    o.x = (v.x - mu) * rstd * gg.x + bb.x;
    o.y = (v.y - mu) * rstd * gg.y + bb.y;
    o.z = (v.z - mu) * rstd * gg.z + bb.z;
    o.w = (v.w - mu) * rstd * gg.w + bb.w;
    *(fl4*)(out + (size_t)row * H_ + t * 4) = o;
}

extern "C" void kernel_launch(void* const* d_in, const int* in_sizes, int n_in,
                              void* d_out, int out_size, void* d_ws, size_t ws_size,
                              hipStream_t stream) {
    const float* x  = (const float*)d_in[0];
    const float* Wq = (const float*)d_in[1];
    const float* bq = (const float*)d_in[2];
    const float* Wk = (const float*)d_in[3];
    const float* bk = (const float*)d_in[4];
    const float* Wv = (const float*)d_in[5];
    const float* bv = (const float*)d_in[6];
    const float* Wo = (const float*)d_in[7];
    const float* bo = (const float*)d_in[8];
    const float* lg = (const float*)d_in[9];
    const float* lb = (const float*)d_in[10];
    float* out = (float*)d_out;

    const size_t MEG = 1024u * 1024u;
    unsigned short* ws16 = (unsigned short*)d_ws;
    unsigned short* xb   = ws16;                  // 4M bf16
    unsigned short* wb   = ws16 + 4 * MEG;        // 4x1M bf16 (Wq,Wk,Wv,Wo)
    unsigned short* qb   = ws16 + 8 * MEG;
    unsigned short* kb   = ws16 + 12 * MEG;
    unsigned short* vT   = ws16 + 16 * MEG;       // transposed V [b,h,d,s]
    unsigned short* ctxb = ws16 + 20 * MEG;
    float* y = (float*)(ws16 + 24 * MEG);         // 4M fp32; total 64 MB

    cast_kernel<<<8192, 256, 0, stream>>>(x, Wq, Wk, Wv, Wo, xb, wb);
    gemm_qkv<<<dim3(32, 8, 3), 512, 0, stream>>>(xb, wb, bq, bk, bv, qb, kb, vT);
    attn_kernel<<<dim3(1024), 256, 0, stream>>>(qb, kb, vT, ctxb);
    gemm_out<<<dim3(32, 8), 512, 0, stream>>>(ctxb, wb + 3 * MEG, bo, x, y);
    ln_kernel<<<4096, 256, 0, stream>>>(y, lg, lb, out);
}

// Round 13
// 207.650 us; speedup vs baseline: 1.0242x; 1.0242x over previous
//
#include <hip/hip_runtime.h>

// B=2,S=2048,H=1024,NH=16,HD=64 fused attention block.
// Round 13: attn reverted to R11 (paired dual-group, uniform 33 steps —
//           the only dispatch-order-proof balance; R5/R12 both prove
//           non-uniform wgs lose). GEMMs: LDS double-buffer -> ONE barrier
//           per kstep (write buf^1 then bar; bar also proves buf reads done).
#define B_  2
#define S_  2048
#define H_  1024
#define NH_ 16
#define HD_ 64
#define M_  (B_*S_)   // 4096 rows

typedef __attribute__((ext_vector_type(8))) __bf16 bf16x8;
typedef __attribute__((ext_vector_type(4))) float  f32x4;
typedef __attribute__((ext_vector_type(8))) unsigned short us8;
typedef __attribute__((ext_vector_type(4))) float  fl4;

__device__ __forceinline__ unsigned short f2bf(float f) {
    unsigned int u = __float_as_uint(f);
    u += 0x7fffu + ((u >> 16) & 1u);          // round-to-nearest-even
    return (unsigned short)(u >> 16);
}

// ---------------- cast fp32 -> bf16 (x and the 4 weights) ----------------
__global__ __launch_bounds__(256) void cast_kernel(
    const float* __restrict__ x,
    const float* __restrict__ wq, const float* __restrict__ wk,
    const float* __restrict__ wv, const float* __restrict__ wo,
    unsigned short* __restrict__ xb, unsigned short* __restrict__ wb) {
    size_t t  = (size_t)blockIdx.x * 256 + threadIdx.x;
    size_t e0 = t * 4;
    const size_t XN = (size_t)M_ * H_;        // 4M
    const float* src;
    unsigned short* dst;
    if (e0 < XN) { src = x + e0; dst = xb + e0; }
    else {
        size_t j = e0 - XN;                    // 0..4M over 4 weights of 1M
        int w = (int)(j >> 20);
        size_t off = j & ((1u << 20) - 1);
        const float* wp = (w == 0) ? wq : (w == 1) ? wk : (w == 2) ? wv : wo;
        src = wp + off; dst = wb + j;
    }
    fl4 v = *(const fl4*)src;
    ushort4 o;
    o.x = f2bf(v.x); o.y = f2bf(v.y); o.z = f2bf(v.z); o.w = f2bf(v.w);
    *(ushort4*)dst = o;
}

// ---------------- QKV GEMM (128x128, 512 thr, reg-prefetch + LDS dbuf) -----
// z==0 -> Q (pre-scaled by 1/8*log2e) ; z==1 -> K ; z==2 -> V transposed.
__global__ __launch_bounds__(512) void gemm_qkv(
    const unsigned short* __restrict__ xb, const unsigned short* __restrict__ wb,
    const float* __restrict__ bq, const float* __restrict__ bk,
    const float* __restrict__ bv,
    unsigned short* __restrict__ qb, unsigned short* __restrict__ kbuf,
    unsigned short* __restrict__ vT) {
    __shared__ __align__(16) unsigned short As[2][128 * 72];
    __shared__ __align__(16) unsigned short Bs[2][128 * 72];
    const int z = blockIdx.z;
    const unsigned short* W = wb + ((size_t)z << 20);
    const int m0 = blockIdx.x * 128, n0 = blockIdx.y * 128;
    const int t = threadIdx.x, lane = t & 63, w = t >> 6;   // w 0..7
    const int wm = w >> 2, wn = w & 3;                      // 2m x 4n
    const int quad = lane >> 4, l16 = lane & 15;
    const int sr = t >> 2, sc = (t & 3) * 16;               // staging row/col
    const unsigned short* ga = xb + (size_t)(m0 + sr) * H_ + sc;
    const unsigned short* gb = W  + (size_t)(n0 + sr) * H_ + sc;

    // preload kstep 0 and publish to buf 0
    us8 a0 = *(const us8*)(ga),     a1 = *(const us8*)(ga + 8);
    us8 b0 = *(const us8*)(gb),     b1 = *(const us8*)(gb + 8);
    *(us8*)&As[0][sr * 72 + sc]     = a0;  *(us8*)&As[0][sr * 72 + sc + 8] = a1;
    *(us8*)&Bs[0][sr * 72 + sc]     = b0;  *(us8*)&Bs[0][sr * 72 + sc + 8] = b1;
    __syncthreads();

    f32x4 acc[4][2] = {};
    for (int ks = 0; ks < 16; ks++) {
        const int buf = ks & 1;
        const bool pf = (ks < 15);
        if (pf) {                        // prefetch next tile (flies under MFMA)
            ga += 64; gb += 64;
            a0 = *(const us8*)(ga);  a1 = *(const us8*)(ga + 8);
            b0 = *(const us8*)(gb);  b1 = *(const us8*)(gb + 8);
        }
#pragma unroll
        for (int kk = 0; kk < 64; kk += 32) {
            bf16x8 af[4], bfr[2];
#pragma unroll
            for (int i = 0; i < 4; i++)
                af[i]  = *(const bf16x8*)&As[buf][(wm * 64 + i * 16 + l16) * 72 + kk + quad * 8];
#pragma unroll
            for (int jn = 0; jn < 2; jn++)
                bfr[jn] = *(const bf16x8*)&Bs[buf][(wn * 32 + jn * 16 + l16) * 72 + kk + quad * 8];
#pragma unroll
            for (int mi = 0; mi < 4; mi++)
#pragma unroll
                for (int ni = 0; ni < 2; ni++)
                    acc[mi][ni] = __builtin_amdgcn_mfma_f32_16x16x32_bf16(
                        af[mi], bfr[ni], acc[mi][ni], 0, 0, 0);
        }
        if (pf) {   // publish to other buffer; barrier also proves buf reads done
            *(us8*)&As[buf ^ 1][sr * 72 + sc]     = a0;
            *(us8*)&As[buf ^ 1][sr * 72 + sc + 8] = a1;
            *(us8*)&Bs[buf ^ 1][sr * 72 + sc]     = b0;
            *(us8*)&Bs[buf ^ 1][sr * 72 + sc + 8] = b1;
            __syncthreads();
        }
    }
    const float* bias = (z == 0) ? bq : (z == 1) ? bk : bv;
    if (z == 2) {
#pragma unroll
        for (int mi = 0; mi < 4; mi++) {
#pragma unroll
            for (int ni = 0; ni < 2; ni++) {
                int col  = n0 + wn * 32 + ni * 16 + l16;   // h*64+d
                float bval = bias[col];
                int row0 = m0 + wm * 64 + mi * 16 + quad * 4;  // b*2048+s
                int bb = row0 >> 11, s0 = row0 & 2047;
                ushort4 pk;
                pk.x = f2bf(acc[mi][ni][0] + bval);
                pk.y = f2bf(acc[mi][ni][1] + bval);
                pk.z = f2bf(acc[mi][ni][2] + bval);
                pk.w = f2bf(acc[mi][ni][3] + bval);
                *(ushort4*)&vT[((size_t)bb * NH_ * HD_ + col) * S_ + s0] = pk;
            }
        }
    } else {
        unsigned short* out = (z == 0) ? qb : kbuf;
        const float qs = (z == 0) ? 0.18033688f : 1.0f;   // (1/8)*log2(e) folded into Q
#pragma unroll
        for (int mi = 0; mi < 4; mi++) {
#pragma unroll
            for (int ni = 0; ni < 2; ni++) {
                int col = n0 + wn * 32 + ni * 16 + l16;
                float bval = bias[col];
#pragma unroll
                for (int r = 0; r < 4; r++) {
                    int row = m0 + wm * 64 + mi * 16 + quad * 4 + r;
                    out[(size_t)row * H_ + col] = f2bf((acc[mi][ni][r] + bval) * qs);
                }
            }
        }
    }
}

// ---------------- Wo GEMM + bias + residual (128x128, 512 thr, dbuf) -------
__global__ __launch_bounds__(512) void gemm_out(
    const unsigned short* __restrict__ ctxb, const unsigned short* __restrict__ wob,
    const float* __restrict__ bo, const float* __restrict__ x,
    float* __restrict__ y) {
    __shared__ __align__(16) unsigned short As[2][128 * 72];
    __shared__ __align__(16) unsigned short Bs[2][128 * 72];
    const int m0 = blockIdx.x * 128, n0 = blockIdx.y * 128;
    const int t = threadIdx.x, lane = t & 63, w = t >> 6;
    const int wm = w >> 2, wn = w & 3;
    const int quad = lane >> 4, l16 = lane & 15;
    const int sr = t >> 2, sc = (t & 3) * 16;
    const unsigned short* ga = ctxb + (size_t)(m0 + sr) * H_ + sc;
    const unsigned short* gb = wob  + (size_t)(n0 + sr) * H_ + sc;

    us8 a0 = *(const us8*)(ga),     a1 = *(const us8*)(ga + 8);
    us8 b0 = *(const us8*)(gb),     b1 = *(const us8*)(gb + 8);
    *(us8*)&As[0][sr * 72 + sc]     = a0;  *(us8*)&As[0][sr * 72 + sc + 8] = a1;
    *(us8*)&Bs[0][sr * 72 + sc]     = b0;  *(us8*)&Bs[0][sr * 72 + sc + 8] = b1;
    __syncthreads();

    f32x4 acc[4][2] = {};
    for (int ks = 0; ks < 16; ks++) {
        const int buf = ks & 1;
        const bool pf = (ks < 15);
        if (pf) {
            ga += 64; gb += 64;
            a0 = *(const us8*)(ga);  a1 = *(const us8*)(ga + 8);
            b0 = *(const us8*)(gb);  b1 = *(const us8*)(gb + 8);
        }
#pragma unroll
        for (int kk = 0; kk < 64; kk += 32) {
            bf16x8 af[4], bfr[2];
#pragma unroll
            for (int i = 0; i < 4; i++)
                af[i]  = *(const bf16x8*)&As[buf][(wm * 64 + i * 16 + l16) * 72 + kk + quad * 8];
#pragma unroll
            for (int jn = 0; jn < 2; jn++)
                bfr[jn] = *(const bf16x8*)&Bs[buf][(wn * 32 + jn * 16 + l16) * 72 + kk + quad * 8];
#pragma unroll
            for (int mi = 0; mi < 4; mi++)
#pragma unroll
                for (int ni = 0; ni < 2; ni++)
                    acc[mi][ni] = __builtin_amdgcn_mfma_f32_16x16x32_bf16(
                        af[mi], bfr[ni], acc[mi][ni], 0, 0, 0);
        }
        if (pf) {
            *(us8*)&As[buf ^ 1][sr * 72 + sc]     = a0;
            *(us8*)&As[buf ^ 1][sr * 72 + sc + 8] = a1;
            *(us8*)&Bs[buf ^ 1][sr * 72 + sc]     = b0;
            *(us8*)&Bs[buf ^ 1][sr * 72 + sc + 8] = b1;
            __syncthreads();
        }
    }
#pragma unroll
    for (int mi = 0; mi < 4; mi++) {
#pragma unroll
        for (int ni = 0; ni < 2; ni++) {
            int col = n0 + wn * 32 + ni * 16 + l16;
            float bval = bo[col];
#pragma unroll
            for (int r = 0; r < 4; r++) {
                size_t idx = (size_t)(m0 + wm * 64 + mi * 16 + quad * 4 + r) * H_ + col;
                y[idx] = acc[mi][ni][r] + bval + x[idx];
            }
        }
    }
}

// ---------------- Flash attention (causal), shared-KV dual-group — R11 -----
__global__ __launch_bounds__(512, 4) void attn_kernel(
    const unsigned short* __restrict__ qb, const unsigned short* __restrict__ kb,
    const unsigned short* __restrict__ vT, unsigned short* __restrict__ ctxb) {
    __shared__ __align__(16) unsigned short Ks[2][64 * 72];   // [key][d]
    __shared__ __align__(16) unsigned short Vt[2][64 * 72];   // [d][key]
    __shared__ __align__(16) unsigned short Ps[128 * 76];     // [wave q-slice][key]
    const int flat = blockIdx.x;                  // 0..255
    const int xcd = flat & 7, slot = flat >> 3;   // slot 0..31
    const int bh  = xcd * 4 + (slot >> 3);
    const int j   = slot & 7;
    const int b = bh >> 4, h = bh & 15;
    const int t = threadIdx.x, lane = t & 63, wid = t >> 6;   // wid 0..7
    const int grp = wid >> 2, wid4 = wid & 3;
    const int quad = lane >> 4, l16 = lane & 15;
    const int sr8 = t >> 3, sc8 = (t & 7) * 8;    // 512-thread staging
    const size_t headoff = (size_t)h * HD_;
    const unsigned short* vtb = vT + ((size_t)(b * NH_ + h) * HD_) * S_;  // [d][s]

    const int p   = j * 2 + grp;      // 0..15
    const int qt1 = p, qt2 = 31 - p;  // 33 steps total per group
    const int q01 = qt1 * 64, q02 = qt2 * 64;

    const size_t qr1 = (size_t)(b * S_ + q01 + wid4 * 16 + l16);
    const size_t qr2 = (size_t)(b * S_ + q02 + wid4 * 16 + l16);
    bf16x8 q1a = *(const bf16x8*)(qb + qr1 * H_ + headoff + quad * 8);
    bf16x8 q1b = *(const bf16x8*)(qb + qr1 * H_ + headoff + 32 + quad * 8);
    bf16x8 q2a = *(const bf16x8*)(qb + qr2 * H_ + headoff + quad * 8);
    bf16x8 q2b = *(const bf16x8*)(qb + qr2 * H_ + headoff + 32 + quad * 8);

    float m1 = -1e30f, l1 = 0.f, m2 = -1e30f, l2 = 0.f;
    f32x4 o1[4] = {}, o2[4] = {};

    const unsigned short* kptr = kb  + (size_t)(b * S_ + sr8) * H_ + headoff + sc8;
    const unsigned short* vptr = vtb + (size_t)sr8 * S_ + sc8;
    us8 nk = *(const us8*)kptr;
    us8 nv = *(const us8*)vptr;
    *(us8*)&Ks[0][sr8 * 72 + sc8] = nk;
    *(us8*)&Vt[0][sr8 * 72 + sc8] = nv;
    __syncthreads();

    for (int s = 0; s < 32; s++) {
        const int buf = s & 1;
        const bool pf = (s < 31);
        if (pf) {
            kptr += (size_t)64 * H_;
            vptr += 64;
            nk = *(const us8*)kptr;
            nv = *(const us8*)vptr;
        }
#pragma unroll
        for (int tile = 0; tile < 2; tile++) {
            const int  qt  = tile ? qt2 : qt1;
            if (s > qt) continue;                 // group-uniform branch
            const bf16x8 qa = tile ? q2a : q1a;
            const bf16x8 qb_ = tile ? q2b : q1b;
            f32x4 sacc[4] = {};
#pragma unroll
            for (int kk = 0; kk < 64; kk += 32) {
                bf16x8 bqf = (kk == 0) ? qa : qb_;
#pragma unroll
                for (int nt = 0; nt < 4; nt++) {
                    bf16x8 ak = *(const bf16x8*)&Ks[buf][(nt * 16 + l16) * 72 + kk + quad * 8];
                    sacc[nt] = __builtin_amdgcn_mfma_f32_16x16x32_bf16(ak, bqf, sacc[nt], 0, 0, 0);
                }
            }
            if (s == qt) {
#pragma unroll
                for (int nt = 0; nt < 4; nt++) {
#pragma unroll
                    for (int r = 0; r < 4; r++) {
                        int key = nt * 16 + quad * 4 + r;
                        if (key > wid4 * 16 + l16) sacc[nt][r] = -1e30f;
                    }
                }
            }
            float mx = sacc[0][0];
#pragma unroll
            for (int nt = 0; nt < 4; nt++)
#pragma unroll
                for (int r = 0; r < 4; r++) mx = fmaxf(mx, sacc[nt][r]);
            mx = fmaxf(mx, __shfl_xor(mx, 16));
            mx = fmaxf(mx, __shfl_xor(mx, 32));
            float m_old = tile ? m2 : m1;
            float m_new = fmaxf(m_old, mx);
            float alpha = exp2f(m_old - m_new);
            float ss = 0.f;
#pragma unroll
            for (int nt = 0; nt < 4; nt++) {
                ushort4 pk;
                float p0 = exp2f(sacc[nt][0] - m_new);
                float p1 = exp2f(sacc[nt][1] - m_new);
                float p2 = exp2f(sacc[nt][2] - m_new);
                float p3 = exp2f(sacc[nt][3] - m_new);
                ss += (p0 + p1) + (p2 + p3);
                pk.x = (unsigned short)(__float_as_uint(p0) >> 16);
                pk.y = (unsigned short)(__float_as_uint(p1) >> 16);
                pk.z = (unsigned short)(__float_as_uint(p2) >> 16);
                pk.w = (unsigned short)(__float_as_uint(p3) >> 16);
                *(ushort4*)&Ps[(wid * 16 + l16) * 76 + nt * 16 + quad * 4] = pk;
            }
            ss += __shfl_xor(ss, 16);
            ss += __shfl_xor(ss, 32);
            if (tile) { l2 = l2 * alpha + ss; m2 = m_new; }
            else      { l1 = l1 * alpha + ss; m1 = m_new; }
            f32x4* oo = tile ? o2 : o1;
#pragma unroll
            for (int dt = 0; dt < 4; dt++)
#pragma unroll
                for (int r = 0; r < 4; r++) oo[dt][r] *= alpha;
            __threadfence_block();
#pragma unroll
            for (int kk = 0; kk < 64; kk += 32) {
                bf16x8 pfr = *(const bf16x8*)&Ps[(wid * 16 + l16) * 76 + kk + quad * 8];
#pragma unroll
                for (int dt = 0; dt < 4; dt++) {
                    bf16x8 vf = *(const bf16x8*)&Vt[buf][(dt * 16 + l16) * 72 + kk + quad * 8];
                    oo[dt] = __builtin_amdgcn_mfma_f32_16x16x32_bf16(vf, pfr, oo[dt], 0, 0, 0);
                }
            }
        }
        if (pf) {
            *(us8*)&Ks[buf ^ 1][sr8 * 72 + sc8] = nk;
            *(us8*)&Vt[buf ^ 1][sr8 * 72 + sc8] = nv;
            __syncthreads();
        }
    }
#pragma unroll
    for (int tile = 0; tile < 2; tile++) {
        const int q0 = tile ? q02 : q01;
        const float inv = 1.0f / (tile ? l2 : l1);
        const f32x4* oo = tile ? o2 : o1;
        size_t row = (size_t)(b * S_ + q0 + wid4 * 16 + l16);
#pragma unroll
        for (int dt = 0; dt < 4; dt++) {
            ushort4 pk;
            pk.x = f2bf(oo[dt][0] * inv);
            pk.y = f2bf(oo[dt][1] * inv);
            pk.z = f2bf(oo[dt][2] * inv);
            pk.w = f2bf(oo[dt][3] * inv);
            *(ushort4*)&ctxb[row * H_ + headoff + dt * 16 + quad * 4] = pk;
        }
    }
}

// ---------------- LayerNorm (1 block per row) ----------------
__global__ __launch_bounds__(256) void ln_kernel(
    const float* __restrict__ y, const float* __restrict__ g,
    const float* __restrict__ bta, float* __restrict__ out) {
    __shared__ float red[8];
    const int row = blockIdx.x, t = threadIdx.x;
    fl4 v = *(const fl4*)(y + (size_t)row * H_ + t * 4);
    float s  = v.x + v.y + v.z + v.w;
    float sq = v.x * v.x + v.y * v.y + v.z * v.z + v.w * v.w;
    for (int m = 1; m < 64; m <<= 1) { s += __shfl_xor(s, m); sq += __shfl_xor(sq, m); }
    const int wid = t >> 6, lane = t & 63;
    if (lane == 0) { red[wid * 2] = s; red[wid * 2 + 1] = sq; }
    __syncthreads();
    s  = red[0] + red[2] + red[4] + red[6];
    sq = red[1] + red[3] + red[5] + red[7];
    float mu   = s * (1.0f / H_);
    float var  = sq * (1.0f / H_) - mu * mu;
    float rstd = rsqrtf(fmaxf(var, 0.f) + 1e-12f);
    fl4 gg = *(const fl4*)(g + t * 4);
    fl4 bb = *(const fl4*)(bta + t * 4);
    fl4 o;
    o.x = (v.x - mu) * rstd * gg.x + bb.x;
    o.y = (v.y - mu) * rstd * gg.y + bb.y;
    o.z = (v.z - mu) * rstd * gg.z + bb.z;
    o.w = (v.w - mu) * rstd * gg.w + bb.w;
    *(fl4*)(out + (size_t)row * H_ + t * 4) = o;
}

extern "C" void kernel_launch(void* const* d_in, const int* in_sizes, int n_in,
                              void* d_out, int out_size, void* d_ws, size_t ws_size,
                              hipStream_t stream) {
    const float* x  = (const float*)d_in[0];
    const float* Wq = (const float*)d_in[1];
    const float* bq = (const float*)d_in[2];
    const float* Wk = (const float*)d_in[3];
    const float* bk = (const float*)d_in[4];
    const float* Wv = (const float*)d_in[5];
    const float* bv = (const float*)d_in[6];
    const float* Wo = (const float*)d_in[7];
    const float* bo = (const float*)d_in[8];
    const float* lg = (const float*)d_in[9];
    const float* lb = (const float*)d_in[10];
    float* out = (float*)d_out;

    const size_t MEG = 1024u * 1024u;
    unsigned short* ws16 = (unsigned short*)d_ws;
    unsigned short* xb   = ws16;                  // 4M bf16
    unsigned short* wb   = ws16 + 4 * MEG;        // 4x1M bf16 (Wq,Wk,Wv,Wo)
    unsigned short* qb   = ws16 + 8 * MEG;
    unsigned short* kb   = ws16 + 12 * MEG;
    unsigned short* vT   = ws16 + 16 * MEG;       // transposed V [b,h,d,s]
    unsigned short* ctxb = ws16 + 20 * MEG;
    float* y = (float*)(ws16 + 24 * MEG);         // 4M fp32; total 64 MB

    cast_kernel<<<8192, 256, 0, stream>>>(x, Wq, Wk, Wv, Wo, xb, wb);
    gemm_qkv<<<dim3(32, 8, 3), 512, 0, stream>>>(xb, wb, bq, bk, bv, qb, kb, vT);
    attn_kernel<<<dim3(256), 512, 0, stream>>>(qb, kb, vT, ctxb);
    gemm_out<<<dim3(32, 8), 512, 0, stream>>>(ctxb, wb + 3 * MEG, bo, x, y);
    ln_kernel<<<4096, 256, 0, stream>>>(y, lg, lb, out);
}

// Round 14
// 194.263 us; speedup vs baseline: 1.0948x; 1.0689x over previous
//
#include <hip/hip_runtime.h>

// B=2,S=2048,H=1024,NH=16,HD=64 fused attention block.
// Round 14: GEMMs reverted to R11 exactly (R13 dbuf regressed). attn = R11
//           structure with all softmax exponentials switched to
//           __builtin_amdgcn_exp2f (bare v_exp_f32, no OCML guard code).
#define B_  2
#define S_  2048
#define H_  1024
#define NH_ 16
#define HD_ 64
#define M_  (B_*S_)   // 4096 rows

typedef __attribute__((ext_vector_type(8))) __bf16 bf16x8;
typedef __attribute__((ext_vector_type(4))) float  f32x4;
typedef __attribute__((ext_vector_type(8))) unsigned short us8;
typedef __attribute__((ext_vector_type(4))) float  fl4;

__device__ __forceinline__ unsigned short f2bf(float f) {
    unsigned int u = __float_as_uint(f);
    u += 0x7fffu + ((u >> 16) & 1u);          // round-to-nearest-even
    return (unsigned short)(u >> 16);
}

// ---------------- cast fp32 -> bf16 (x and the 4 weights) ----------------
__global__ __launch_bounds__(256) void cast_kernel(
    const float* __restrict__ x,
    const float* __restrict__ wq, const float* __restrict__ wk,
    const float* __restrict__ wv, const float* __restrict__ wo,
    unsigned short* __restrict__ xb, unsigned short* __restrict__ wb) {
    size_t t  = (size_t)blockIdx.x * 256 + threadIdx.x;
    size_t e0 = t * 4;
    const size_t XN = (size_t)M_ * H_;        // 4M
    const float* src;
    unsigned short* dst;
    if (e0 < XN) { src = x + e0; dst = xb + e0; }
    else {
        size_t j = e0 - XN;                    // 0..4M over 4 weights of 1M
        int w = (int)(j >> 20);
        size_t off = j & ((1u << 20) - 1);
        const float* wp = (w == 0) ? wq : (w == 1) ? wk : (w == 2) ? wv : wo;
        src = wp + off; dst = wb + j;
    }
    fl4 v = *(const fl4*)src;
    ushort4 o;
    o.x = f2bf(v.x); o.y = f2bf(v.y); o.z = f2bf(v.z); o.w = f2bf(v.w);
    *(ushort4*)dst = o;
}

// ---------------- QKV GEMM (128x128, 512 thr, reg-prefetch) — R11 ----------
// z==0 -> Q (pre-scaled by 1/8*log2e) ; z==1 -> K ; z==2 -> V transposed.
__global__ __launch_bounds__(512) void gemm_qkv(
    const unsigned short* __restrict__ xb, const unsigned short* __restrict__ wb,
    const float* __restrict__ bq, const float* __restrict__ bk,
    const float* __restrict__ bv,
    unsigned short* __restrict__ qb, unsigned short* __restrict__ kbuf,
    unsigned short* __restrict__ vT) {
    __shared__ __align__(16) unsigned short As[128 * 72];
    __shared__ __align__(16) unsigned short Bs[128 * 72];
    const int z = blockIdx.z;
    const unsigned short* W = wb + ((size_t)z << 20);
    const int m0 = blockIdx.x * 128, n0 = blockIdx.y * 128;
    const int t = threadIdx.x, lane = t & 63, w = t >> 6;   // w 0..7
    const int wm = w >> 2, wn = w & 3;                      // 2m x 4n
    const int quad = lane >> 4, l16 = lane & 15;
    const int sr = t >> 2, sc = (t & 3) * 16;               // staging row/col
    const unsigned short* ga = xb + (size_t)(m0 + sr) * H_ + sc;
    const unsigned short* gb = W  + (size_t)(n0 + sr) * H_ + sc;

    us8 a0 = *(const us8*)(ga),     a1 = *(const us8*)(ga + 8);
    us8 b0 = *(const us8*)(gb),     b1 = *(const us8*)(gb + 8);

    f32x4 acc[4][2] = {};
    for (int k0 = 0; k0 < H_; k0 += 64) {
        if (k0) __syncthreads();        // LDS readers of previous kstep done
        *(us8*)&As[sr * 72 + sc]     = a0;  *(us8*)&As[sr * 72 + sc + 8] = a1;
        *(us8*)&Bs[sr * 72 + sc]     = b0;  *(us8*)&Bs[sr * 72 + sc + 8] = b1;
        __syncthreads();                 // tile published
        if (k0 + 64 < H_) {              // prefetch next tile (flies under MFMA)
            ga += 64; gb += 64;
            a0 = *(const us8*)(ga);  a1 = *(const us8*)(ga + 8);
            b0 = *(const us8*)(gb);  b1 = *(const us8*)(gb + 8);
        }
#pragma unroll
        for (int kk = 0; kk < 64; kk += 32) {
            bf16x8 af[4], bfr[2];
#pragma unroll
            for (int i = 0; i < 4; i++)
                af[i]  = *(const bf16x8*)&As[(wm * 64 + i * 16 + l16) * 72 + kk + quad * 8];
#pragma unroll
            for (int jn = 0; jn < 2; jn++)
                bfr[jn] = *(const bf16x8*)&Bs[(wn * 32 + jn * 16 + l16) * 72 + kk + quad * 8];
#pragma unroll
            for (int mi = 0; mi < 4; mi++)
#pragma unroll
                for (int ni = 0; ni < 2; ni++)
                    acc[mi][ni] = __builtin_amdgcn_mfma_f32_16x16x32_bf16(
                        af[mi], bfr[ni], acc[mi][ni], 0, 0, 0);
        }
    }
    const float* bias = (z == 0) ? bq : (z == 1) ? bk : bv;
    if (z == 2) {
#pragma unroll
        for (int mi = 0; mi < 4; mi++) {
#pragma unroll
            for (int ni = 0; ni < 2; ni++) {
                int col  = n0 + wn * 32 + ni * 16 + l16;   // h*64+d
                float bval = bias[col];
                int row0 = m0 + wm * 64 + mi * 16 + quad * 4;  // b*2048+s
                int bb = row0 >> 11, s0 = row0 & 2047;
                ushort4 pk;
                pk.x = f2bf(acc[mi][ni][0] + bval);
                pk.y = f2bf(acc[mi][ni][1] + bval);
                pk.z = f2bf(acc[mi][ni][2] + bval);
                pk.w = f2bf(acc[mi][ni][3] + bval);
                *(ushort4*)&vT[((size_t)bb * NH_ * HD_ + col) * S_ + s0] = pk;
            }
        }
    } else {
        unsigned short* out = (z == 0) ? qb : kbuf;
        const float qs = (z == 0) ? 0.18033688f : 1.0f;   // (1/8)*log2(e) folded into Q
#pragma unroll
        for (int mi = 0; mi < 4; mi++) {
#pragma unroll
            for (int ni = 0; ni < 2; ni++) {
                int col = n0 + wn * 32 + ni * 16 + l16;
                float bval = bias[col];
#pragma unroll
                for (int r = 0; r < 4; r++) {
                    int row = m0 + wm * 64 + mi * 16 + quad * 4 + r;
                    out[(size_t)row * H_ + col] = f2bf((acc[mi][ni][r] + bval) * qs);
                }
            }
        }
    }
}

// ---------------- Wo GEMM + bias + residual (128x128, 512 thr) — R11 -------
__global__ __launch_bounds__(512) void gemm_out(
    const unsigned short* __restrict__ ctxb, const unsigned short* __restrict__ wob,
    const float* __restrict__ bo, const float* __restrict__ x,
    float* __restrict__ y) {
    __shared__ __align__(16) unsigned short As[128 * 72];
    __shared__ __align__(16) unsigned short Bs[128 * 72];
    const int m0 = blockIdx.x * 128, n0 = blockIdx.y * 128;
    const int t = threadIdx.x, lane = t & 63, w = t >> 6;
    const int wm = w >> 2, wn = w & 3;
    const int quad = lane >> 4, l16 = lane & 15;
    const int sr = t >> 2, sc = (t & 3) * 16;
    const unsigned short* ga = ctxb + (size_t)(m0 + sr) * H_ + sc;
    const unsigned short* gb = wob  + (size_t)(n0 + sr) * H_ + sc;

    us8 a0 = *(const us8*)(ga),     a1 = *(const us8*)(ga + 8);
    us8 b0 = *(const us8*)(gb),     b1 = *(const us8*)(gb + 8);

    f32x4 acc[4][2] = {};
    for (int k0 = 0; k0 < H_; k0 += 64) {
        if (k0) __syncthreads();
        *(us8*)&As[sr * 72 + sc]     = a0;  *(us8*)&As[sr * 72 + sc + 8] = a1;
        *(us8*)&Bs[sr * 72 + sc]     = b0;  *(us8*)&Bs[sr * 72 + sc + 8] = b1;
        __syncthreads();
        if (k0 + 64 < H_) {
            ga += 64; gb += 64;
            a0 = *(const us8*)(ga);  a1 = *(const us8*)(ga + 8);
            b0 = *(const us8*)(gb);  b1 = *(const us8*)(gb + 8);
        }
#pragma unroll
        for (int kk = 0; kk < 64; kk += 32) {
            bf16x8 af[4], bfr[2];
#pragma unroll
            for (int i = 0; i < 4; i++)
                af[i]  = *(const bf16x8*)&As[(wm * 64 + i * 16 + l16) * 72 + kk + quad * 8];
#pragma unroll
            for (int jn = 0; jn < 2; jn++)
                bfr[jn] = *(const bf16x8*)&Bs[(wn * 32 + jn * 16 + l16) * 72 + kk + quad * 8];
#pragma unroll
            for (int mi = 0; mi < 4; mi++)
#pragma unroll
                for (int ni = 0; ni < 2; ni++)
                    acc[mi][ni] = __builtin_amdgcn_mfma_f32_16x16x32_bf16(
                        af[mi], bfr[ni], acc[mi][ni], 0, 0, 0);
        }
    }
#pragma unroll
    for (int mi = 0; mi < 4; mi++) {
#pragma unroll
        for (int ni = 0; ni < 2; ni++) {
            int col = n0 + wn * 32 + ni * 16 + l16;
            float bval = bo[col];
#pragma unroll
            for (int r = 0; r < 4; r++) {
                size_t idx = (size_t)(m0 + wm * 64 + mi * 16 + quad * 4 + r) * H_ + col;
                y[idx] = acc[mi][ni][r] + bval + x[idx];
            }
        }
    }
}

// ---------------- Flash attention (causal), shared-KV dual-group -----------
// R11 structure; exponentials via __builtin_amdgcn_exp2f (bare v_exp_f32).
__global__ __launch_bounds__(512, 4) void attn_kernel(
    const unsigned short* __restrict__ qb, const unsigned short* __restrict__ kb,
    const unsigned short* __restrict__ vT, unsigned short* __restrict__ ctxb) {
    __shared__ __align__(16) unsigned short Ks[2][64 * 72];   // [key][d]
    __shared__ __align__(16) unsigned short Vt[2][64 * 72];   // [d][key]
    __shared__ __align__(16) unsigned short Ps[128 * 76];     // [wave q-slice][key]
    const int flat = blockIdx.x;                  // 0..255
    const int xcd = flat & 7, slot = flat >> 3;   // slot 0..31
    const int bh  = xcd * 4 + (slot >> 3);
    const int j   = slot & 7;
    const int b = bh >> 4, h = bh & 15;
    const int t = threadIdx.x, lane = t & 63, wid = t >> 6;   // wid 0..7
    const int grp = wid >> 2, wid4 = wid & 3;
    const int quad = lane >> 4, l16 = lane & 15;
    const int sr8 = t >> 3, sc8 = (t & 7) * 8;    // 512-thread staging
    const size_t headoff = (size_t)h * HD_;
    const unsigned short* vtb = vT + ((size_t)(b * NH_ + h) * HD_) * S_;  // [d][s]

    const int p   = j * 2 + grp;      // 0..15
    const int qt1 = p, qt2 = 31 - p;  // 33 steps total per group
    const int q01 = qt1 * 64, q02 = qt2 * 64;

    const size_t qr1 = (size_t)(b * S_ + q01 + wid4 * 16 + l16);
    const size_t qr2 = (size_t)(b * S_ + q02 + wid4 * 16 + l16);
    bf16x8 q1a = *(const bf16x8*)(qb + qr1 * H_ + headoff + quad * 8);
    bf16x8 q1b = *(const bf16x8*)(qb + qr1 * H_ + headoff + 32 + quad * 8);
    bf16x8 q2a = *(const bf16x8*)(qb + qr2 * H_ + headoff + quad * 8);
    bf16x8 q2b = *(const bf16x8*)(qb + qr2 * H_ + headoff + 32 + quad * 8);

    float m1 = -1e30f, l1 = 0.f, m2 = -1e30f, l2 = 0.f;
    f32x4 o1[4] = {}, o2[4] = {};

    const unsigned short* kptr = kb  + (size_t)(b * S_ + sr8) * H_ + headoff + sc8;
    const unsigned short* vptr = vtb + (size_t)sr8 * S_ + sc8;
    us8 nk = *(const us8*)kptr;
    us8 nv = *(const us8*)vptr;
    *(us8*)&Ks[0][sr8 * 72 + sc8] = nk;
    *(us8*)&Vt[0][sr8 * 72 + sc8] = nv;
    __syncthreads();

    for (int s = 0; s < 32; s++) {
        const int buf = s & 1;
        const bool pf = (s < 31);
        if (pf) {
            kptr += (size_t)64 * H_;
            vptr += 64;
            nk = *(const us8*)kptr;
            nv = *(const us8*)vptr;
        }
#pragma unroll
        for (int tile = 0; tile < 2; tile++) {
            const int  qt  = tile ? qt2 : qt1;
            if (s > qt) continue;                 // group-uniform branch
            const bf16x8 qa = tile ? q2a : q1a;
            const bf16x8 qb_ = tile ? q2b : q1b;
            f32x4 sacc[4] = {};
#pragma unroll
            for (int kk = 0; kk < 64; kk += 32) {
                bf16x8 bqf = (kk == 0) ? qa : qb_;
#pragma unroll
                for (int nt = 0; nt < 4; nt++) {
                    bf16x8 ak = *(const bf16x8*)&Ks[buf][(nt * 16 + l16) * 72 + kk + quad * 8];
                    sacc[nt] = __builtin_amdgcn_mfma_f32_16x16x32_bf16(ak, bqf, sacc[nt], 0, 0, 0);
                }
            }
            if (s == qt) {
#pragma unroll
                for (int nt = 0; nt < 4; nt++) {
#pragma unroll
                    for (int r = 0; r < 4; r++) {
                        int key = nt * 16 + quad * 4 + r;
                        if (key > wid4 * 16 + l16) sacc[nt][r] = -1e30f;
                    }
                }
            }
            float mx = sacc[0][0];
#pragma unroll
            for (int nt = 0; nt < 4; nt++)
#pragma unroll
                for (int r = 0; r < 4; r++) mx = fmaxf(mx, sacc[nt][r]);
            mx = fmaxf(mx, __shfl_xor(mx, 16));
            mx = fmaxf(mx, __shfl_xor(mx, 32));
            float m_old = tile ? m2 : m1;
            float m_new = fmaxf(m_old, mx);
            float alpha = __builtin_amdgcn_exp2f(m_old - m_new);
            float ss = 0.f;
#pragma unroll
            for (int nt = 0; nt < 4; nt++) {
                ushort4 pk;
                float p0 = __builtin_amdgcn_exp2f(sacc[nt][0] - m_new);
                float p1 = __builtin_amdgcn_exp2f(sacc[nt][1] - m_new);
                float p2 = __builtin_amdgcn_exp2f(sacc[nt][2] - m_new);
                float p3 = __builtin_amdgcn_exp2f(sacc[nt][3] - m_new);
                ss += (p0 + p1) + (p2 + p3);
                pk.x = (unsigned short)(__float_as_uint(p0) >> 16);
                pk.y = (unsigned short)(__float_as_uint(p1) >> 16);
                pk.z = (unsigned short)(__float_as_uint(p2) >> 16);
                pk.w = (unsigned short)(__float_as_uint(p3) >> 16);
                *(ushort4*)&Ps[(wid * 16 + l16) * 76 + nt * 16 + quad * 4] = pk;
            }
            ss += __shfl_xor(ss, 16);
            ss += __shfl_xor(ss, 32);
            if (tile) { l2 = l2 * alpha + ss; m2 = m_new; }
            else      { l1 = l1 * alpha + ss; m1 = m_new; }
            f32x4* oo = tile ? o2 : o1;
#pragma unroll
            for (int dt = 0; dt < 4; dt++)
#pragma unroll
                for (int r = 0; r < 4; r++) oo[dt][r] *= alpha;
            __threadfence_block();
#pragma unroll
            for (int kk = 0; kk < 64; kk += 32) {
                bf16x8 pfr = *(const bf16x8*)&Ps[(wid * 16 + l16) * 76 + kk + quad * 8];
#pragma unroll
                for (int dt = 0; dt < 4; dt++) {
                    bf16x8 vf = *(const bf16x8*)&Vt[buf][(dt * 16 + l16) * 72 + kk + quad * 8];
                    oo[dt] = __builtin_amdgcn_mfma_f32_16x16x32_bf16(vf, pfr, oo[dt], 0, 0, 0);
                }
            }
        }
        if (pf) {
            *(us8*)&Ks[buf ^ 1][sr8 * 72 + sc8] = nk;
            *(us8*)&Vt[buf ^ 1][sr8 * 72 + sc8] = nv;
            __syncthreads();
        }
    }
#pragma unroll
    for (int tile = 0; tile < 2; tile++) {
        const int q0 = tile ? q02 : q01;
        const float inv = 1.0f / (tile ? l2 : l1);
        const f32x4* oo = tile ? o2 : o1;
        size_t row = (size_t)(b * S_ + q0 + wid4 * 16 + l16);
#pragma unroll
        for (int dt = 0; dt < 4; dt++) {
            ushort4 pk;
            pk.x = f2bf(oo[dt][0] * inv);
            pk.y = f2bf(oo[dt][1] * inv);
            pk.z = f2bf(oo[dt][2] * inv);
            pk.w = f2bf(oo[dt][3] * inv);
            *(ushort4*)&ctxb[row * H_ + headoff + dt * 16 + quad * 4] = pk;
        }
    }
}

// ---------------- LayerNorm (1 block per row) ----------------
__global__ __launch_bounds__(256) void ln_kernel(
    const float* __restrict__ y, const float* __restrict__ g,
    const float* __restrict__ bta, float* __restrict__ out) {
    __shared__ float red[8];
    const int row = blockIdx.x, t = threadIdx.x;
    fl4 v = *(const fl4*)(y + (size_t)row * H_ + t * 4);
    float s  = v.x + v.y + v.z + v.w;
    float sq = v.x * v.x + v.y * v.y + v.z * v.z + v.w * v.w;
    for (int m = 1; m < 64; m <<= 1) { s += __shfl_xor(s, m); sq += __shfl_xor(sq, m); }
    const int wid = t >> 6, lane = t & 63;
    if (lane == 0) { red[wid * 2] = s; red[wid * 2 + 1] = sq; }
    __syncthreads();
    s  = red[0] + red[2] + red[4] + red[6];
    sq = red[1] + red[3] + red[5] + red[7];
    float mu   = s * (1.0f / H_);
    float var  = sq * (1.0f / H_) - mu * mu;
    float rstd = rsqrtf(fmaxf(var, 0.f) + 1e-12f);
    fl4 gg = *(const fl4*)(g + t * 4);
    fl4 bb = *(const fl4*)(bta + t * 4);
    fl4 o;
    o.x = (v.x - mu) * rstd * gg.x + bb.x;
    o.y = (v.y - mu) * rstd * gg.y + bb.y;
    o.z = (v.z - mu) * rstd * gg.z + bb.z;
    o.w = (v.w - mu) * rstd * gg.w + bb.w;
    *(fl4*)(out + (size_t)row * H_ + t * 4) = o;
}

extern "C" void kernel_launch(void* const* d_in, const int* in_sizes, int n_in,
                              void* d_out, int out_size, void* d_ws, size_t ws_size,
                              hipStream_t stream) {
    const float* x  = (const float*)d_in[0];
    const float* Wq = (const float*)d_in[1];
    const float* bq = (const float*)d_in[2];
    const float* Wk = (const float*)d_in[3];
    const float* bk = (const float*)d_in[4];
    const float* Wv = (const float*)d_in[5];
    const float* bv = (const float*)d_in[6];
    const float* Wo = (const float*)d_in[7];
    const float* bo = (const float*)d_in[8];
    const float* lg = (const float*)d_in[9];
    const float* lb = (const float*)d_in[10];
    float* out = (float*)d_out;

    const size_t MEG = 1024u * 1024u;
    unsigned short* ws16 = (unsigned short*)d_ws;
    unsigned short* xb   = ws16;                  // 4M bf16
    unsigned short* wb   = ws16 + 4 * MEG;        // 4x1M bf16 (Wq,Wk,Wv,Wo)
    unsigned short* qb   = ws16 + 8 * MEG;
    unsigned short* kb   = ws16 + 12 * MEG;
    unsigned short* vT   = ws16 + 16 * MEG;       // transposed V [b,h,d,s]
    unsigned short* ctxb = ws16 + 20 * MEG;
    float* y = (float*)(ws16 + 24 * MEG);         // 4M fp32; total 64 MB

    cast_kernel<<<8192, 256, 0, stream>>>(x, Wq, Wk, Wv, Wo, xb, wb);
    gemm_qkv<<<dim3(32, 8, 3), 512, 0, stream>>>(xb, wb, bq, bk, bv, qb, kb, vT);
    attn_kernel<<<dim3(256), 512, 0, stream>>>(qb, kb, vT, ctxb);
    gemm_out<<<dim3(32, 8), 512, 0, stream>>>(ctxb, wb + 3 * MEG, bo, x, y);
    ln_kernel<<<4096, 256, 0, stream>>>(y, lg, lb, out);
}